// Round 6
// baseline (395.201 us; speedup 1.0000x reference)
//
#include <hip/hip_runtime.h>

#define HID 128
#define C2 256   // HEADS*HID
#define NEG 0.2f

typedef __bf16 v8bf __attribute__((ext_vector_type(8)));
typedef float  v4f  __attribute__((ext_vector_type(4)));
typedef unsigned short us8 __attribute__((ext_vector_type(8)));

__device__ __forceinline__ float bf2f(unsigned short u) {
    union { float f; unsigned int i; } v; v.i = ((unsigned int)u) << 16; return v.f;
}
__device__ __forceinline__ unsigned short f2bf(float f) {
    union { float f; unsigned int i; } v; v.f = f;
    unsigned int r = v.i + 0x7FFFu + ((v.i >> 16) & 1u);
    return (unsigned short)(r >> 16);
}
__device__ __forceinline__ float lrelu(float x) { return x > 0.f ? x : NEG * x; }

// ---------------- pack W[K,N] fp32 -> bf16 MFMA-B-fragment order ----------------
// frag idx = (nt*ksteps + k0)*64 + lane; element j = W[k0*32+(lane>>4)*8+j][nt*16+(lane&15)]
__global__ __launch_bounds__(256) void packB(const float* __restrict__ W,
                                             unsigned short* __restrict__ out,
                                             int K, int N) {
    int idx = blockIdx.x * 256 + threadIdx.x;
    int ksteps = K >> 5;
    int total = (N >> 4) * ksteps * 64;
    if (idx >= total) return;
    int lane = idx & 63;
    int rest = idx >> 6;
    int nt = rest / ksteps, k0 = rest - nt * ksteps;
    int n = nt * 16 + (lane & 15);
    int kb = k0 * 32 + (lane >> 4) * 8;
    us8 v;
#pragma unroll
    for (int j = 0; j < 8; ++j) v[j] = f2bf(W[(size_t)(kb + j) * N + n]);
    *(us8*)(out + (size_t)idx * 8) = v;
}

// ---------------- CSR build ----------------
__global__ void zero_int(int* p, int n) {
    int i = blockIdx.x * 256 + threadIdx.x;
    if (i < n) p[i] = 0;
}

__global__ void hist_kernel(const int* __restrict__ ei, int* __restrict__ cnt, int E, int N) {
    int i = blockIdx.x * 256 + threadIdx.x;
    if (i >= E + N) return;
    int d = (i < E) ? ei[E + i] : (i - E);
    atomicAdd(&cnt[d], 1);
}

__global__ __launch_bounds__(256) void scanA(const int* __restrict__ cnt, int* __restrict__ rs,
                                             int* __restrict__ part, int N) {
    __shared__ int s[256];
    int t = threadIdx.x, i = blockIdx.x * 256 + t;
    int v = (i < N) ? cnt[i] : 0;
    s[t] = v; __syncthreads();
    for (int off = 1; off < 256; off <<= 1) {
        int x = (t >= off) ? s[t - off] : 0;
        __syncthreads();
        s[t] += x;
        __syncthreads();
    }
    if (i < N) rs[i] = s[t] - v;
    if (t == 255) part[blockIdx.x] = s[255];
}

__global__ __launch_bounds__(256) void scanB(int* __restrict__ part, int n) {
    __shared__ int s[256];
    int t = threadIdx.x;
    int v = (t < n) ? part[t] : 0;
    s[t] = v; __syncthreads();
    for (int off = 1; off < 256; off <<= 1) {
        int x = (t >= off) ? s[t - off] : 0;
        __syncthreads();
        s[t] += x;
        __syncthreads();
    }
    if (t < n) part[t] = s[t] - v;
}

__global__ void scanC(int* __restrict__ rs, const int* __restrict__ part,
                      int* __restrict__ cur, int N, int ET) {
    int i = blockIdx.x * 256 + threadIdx.x;
    if (i < N) {
        int v = rs[i] + part[blockIdx.x];
        rs[i] = v;
        cur[i] = v;
    }
    if (i == 0) rs[N] = ET;
}

__global__ void scatter_kernel(const int* __restrict__ ei, int* __restrict__ cur,
                               int* __restrict__ csr, int E, int N) {
    int i = blockIdx.x * 256 + threadIdx.x;
    if (i >= E + N) return;
    int s, d;
    if (i < E) { s = ei[i]; d = ei[E + i]; } else { s = d = i - E; }
    int pos = atomicAdd(&cur[d], 1);
    csr[pos] = s;
}

// ---------------- GEMM (layers 1,2): fused alpha dots; G m-tiles per wave ----------------
// wave = (16*G) rows x 128 cols (one head g). B from packed fragments (coalesced).
// mfma layout: A[m=l16][k=quad*8+j], D col=l16,row=quad*4+r
template<bool AFP32, int G>
__global__ __launch_bounds__(256) void gemm_alpha(const void* __restrict__ Av,
                                                  const unsigned short* __restrict__ Bp,
                                                  const float* __restrict__ asrc,
                                                  const float* __restrict__ adst,
                                                  float* __restrict__ asd,
                                                  unsigned short* __restrict__ C,
                                                  int M, int N, int K) {
    int ksteps = K >> 5;
    int ngrp = N >> 7;
    int mtiles = M >> 4;
    int groups = (mtiles + G - 1) / G;
    int w = (blockIdx.x << 2) + (threadIdx.x >> 6);
    int mp = w / ngrp, g = w - mp * ngrp;
    if (mp >= groups) return;
    int lane = threadIdx.x & 63;
    int l16 = lane & 15, quad = lane >> 4;

    int mrow[G];
#pragma unroll
    for (int gi = 0; gi < G; ++gi) {
        int mt = mp * G + gi;
        mrow[gi] = (mt < mtiles ? mt : mtiles - 1) * 16 + l16;
    }

    const unsigned short* Bf = Bp + ((size_t)(g * 8) * ksteps << 9) + lane * 8;
    v4f acc[G][8];
#pragma unroll
    for (int gi = 0; gi < G; ++gi)
#pragma unroll
        for (int t = 0; t < 8; ++t) acc[gi][t] = (v4f){0, 0, 0, 0};

    for (int k0 = 0; k0 < ksteps; ++k0) {
        v8bf a[G];
        if (AFP32) {
            const float* A = (const float*)Av;
#pragma unroll
            for (int gi = 0; gi < G; ++gi) {
                const float* p = A + (size_t)mrow[gi] * K + k0 * 32 + quad * 8;
                float4 u0 = *(const float4*)p, u1 = *(const float4*)(p + 4);
                a[gi][0]=(__bf16)u0.x; a[gi][1]=(__bf16)u0.y; a[gi][2]=(__bf16)u0.z; a[gi][3]=(__bf16)u0.w;
                a[gi][4]=(__bf16)u1.x; a[gi][5]=(__bf16)u1.y; a[gi][6]=(__bf16)u1.z; a[gi][7]=(__bf16)u1.w;
            }
        } else {
            const unsigned short* A = (const unsigned short*)Av;
#pragma unroll
            for (int gi = 0; gi < G; ++gi)
                a[gi] = *(const v8bf*)(A + (size_t)mrow[gi] * K + k0 * 32 + quad * 8);
        }
#pragma unroll
        for (int t = 0; t < 8; ++t) {
            v8bf bfr = *(const v8bf*)(Bf + ((size_t)(t * ksteps + k0) << 9));
#pragma unroll
            for (int gi = 0; gi < G; ++gi)
                acc[gi][t] = __builtin_amdgcn_mfma_f32_16x16x32_bf16(a[gi], bfr, acc[gi][t], 0, 0, 0);
        }
    }

    int n0 = g << 7;
    float sv[8], dv[8];
#pragma unroll
    for (int t = 0; t < 8; ++t) {
        int col = n0 + t * 16 + l16;
        sv[t] = asrc[col];
        dv[t] = adst[col];
    }
    // epilogue per m-tile: store rounded h, alpha dots from rounded values
#pragma unroll
    for (int gi = 0; gi < G; ++gi) {
        int mt = mp * G + gi;
        if (mt >= mtiles) break;
        int row0 = mt * 16 + quad * 4;
#pragma unroll
        for (int r = 0; r < 4; ++r) {
            float sa = 0.f, sd = 0.f;
#pragma unroll
            for (int t = 0; t < 8; ++t) {
                int col = n0 + t * 16 + l16;
                unsigned short hb = f2bf(acc[gi][t][r]);
                C[(size_t)(row0 + r) * N + col] = hb;
                float hv = bf2f(hb);
                sa += hv * sv[t];
                sd += hv * dv[t];
            }
#pragma unroll
            for (int off = 8; off; off >>= 1) {
                sa += __shfl_xor(sa, off);
                sd += __shfl_xor(sd, off);
            }
            if (l16 == 0) {
                int row = row0 + r;
                asd[(size_t)row * 4 + g]     = sa;
                asd[(size_t)row * 4 + 2 + g] = sd;
            }
        }
    }
}

// ---------------- single-pass per-destination softmax+aggregate; one wave per dest ----------------
__global__ __launch_bounds__(256) void agg_kernel(const int* __restrict__ rs,
                                                  const int* __restrict__ csr,
                                                  const unsigned short* __restrict__ h,
                                                  const float* __restrict__ asd,
                                                  const float* __restrict__ bias,
                                                  unsigned short* __restrict__ out, int N) {
    int d = blockIdx.x * 4 + (threadIdx.x >> 6);
    if (d >= N) return;
    int lane = threadIdx.x & 63;
    int beg = rs[d], end = rs[d + 1];
    int e2 = lane >> 5;
    int sub = lane & 31;
    int head = sub >> 4;
    float adh = asd[(size_t)d * 4 + 2 + head];
    int cbase = sub * 8;
    float a[8];
#pragma unroll
    for (int j = 0; j < 8; ++j) a[j] = 0.f;
    float den = 0.f;
#pragma unroll 4
    for (int i = beg; i < end; i += 2) {
        int ei = i + e2;
        bool valid = ei < end;
        int s = csr[valid ? ei : end - 1];
        float e = lrelu(asd[(size_t)s * 4 + head] + adh);
        float wgt = valid ? __expf(e) : 0.f;
        den += wgt;
        us8 hv = *(const us8*)(h + (size_t)s * C2 + cbase);
#pragma unroll
        for (int j = 0; j < 8; ++j) a[j] += wgt * bf2f(hv[j]);
    }
#pragma unroll
    for (int j = 0; j < 8; ++j) a[j] += __shfl_xor(a[j], 32);
    den += __shfl_xor(den, 32);
    if (e2 == 0) {
        float rden = 1.f / (den + 1e-16f);
        us8 o;
#pragma unroll
        for (int j = 0; j < 8; ++j) o[j] = f2bf(fmaxf(a[j] * rden + bias[cbase + j], 0.f));
        *(us8*)(out + (size_t)d * C2 + cbase) = o;
    }
}

// ---------------- post-MLP fused: t = A@Wp1 + bp1; out = sigmoid(t.Wp2 + bp2); G m-tiles/wave ----------------
template<int G>
__global__ __launch_bounds__(256) void gemm_final(const unsigned short* __restrict__ A,
                                                  const unsigned short* __restrict__ Bp,
                                                  const float* __restrict__ bp1,
                                                  const float* __restrict__ wp2,
                                                  const float* __restrict__ bp2,
                                                  float* __restrict__ out,
                                                  int M, int K) {
    int ksteps = K >> 5;                 // 8
    int mtiles = M >> 4;
    int groups = (mtiles + G - 1) / G;
    int mp = (blockIdx.x << 2) + (threadIdx.x >> 6);
    if (mp >= groups) return;
    int lane = threadIdx.x & 63;
    int l16 = lane & 15, quad = lane >> 4;

    int mrow[G];
#pragma unroll
    for (int gi = 0; gi < G; ++gi) {
        int mt = mp * G + gi;
        mrow[gi] = (mt < mtiles ? mt : mtiles - 1) * 16 + l16;
    }

    const unsigned short* Bf = Bp + lane * 8;
    v4f acc[G][8];
#pragma unroll
    for (int gi = 0; gi < G; ++gi)
#pragma unroll
        for (int t = 0; t < 8; ++t) acc[gi][t] = (v4f){0, 0, 0, 0};
    for (int k0 = 0; k0 < ksteps; ++k0) {
        v8bf a[G];
#pragma unroll
        for (int gi = 0; gi < G; ++gi)
            a[gi] = *(const v8bf*)(A + (size_t)mrow[gi] * K + k0 * 32 + quad * 8);
#pragma unroll
        for (int t = 0; t < 8; ++t) {
            v8bf bfr = *(const v8bf*)(Bf + ((size_t)(t * ksteps + k0) << 9));
#pragma unroll
            for (int gi = 0; gi < G; ++gi)
                acc[gi][t] = __builtin_amdgcn_mfma_f32_16x16x32_bf16(a[gi], bfr, acc[gi][t], 0, 0, 0);
        }
    }
    float wv[8], bv[8];
#pragma unroll
    for (int t = 0; t < 8; ++t) {
        int col = t * 16 + l16;
        wv[t] = wp2[col];
        bv[t] = bp1[col];
    }
    float bias2 = bp2[0];
#pragma unroll
    for (int gi = 0; gi < G; ++gi) {
        int mt = mp * G + gi;
        if (mt >= mtiles) break;
        int row0 = mt * 16 + quad * 4;
#pragma unroll
        for (int r = 0; r < 4; ++r) {
            float s = 0.f;
#pragma unroll
            for (int t = 0; t < 8; ++t) s += (acc[gi][t][r] + bv[t]) * wv[t];
#pragma unroll
            for (int off = 8; off; off >>= 1) s += __shfl_xor(s, off);
            if (l16 == 0) {
                float xv = s + bias2;
                out[row0 + r] = 1.f / (1.f + __expf(-xv));
            }
        }
    }
}

extern "C" void kernel_launch(void* const* d_in, const int* in_sizes, int n_in,
                              void* d_out, int out_size, void* d_ws, size_t ws_size,
                              hipStream_t stream) {
    const float* x   = (const float*)d_in[0];
    const int*   ei  = (const int*)d_in[1];
    const float* W1  = (const float*)d_in[2];
    const float* as1 = (const float*)d_in[3];
    const float* ad1 = (const float*)d_in[4];
    const float* b1  = (const float*)d_in[5];
    const float* W2  = (const float*)d_in[6];
    const float* as2 = (const float*)d_in[7];
    const float* ad2 = (const float*)d_in[8];
    const float* b2  = (const float*)d_in[9];
    const float* Wp1 = (const float*)d_in[10];
    const float* bp1 = (const float*)d_in[11];
    const float* Wp2 = (const float*)d_in[12];
    const float* bp2 = (const float*)d_in[13];
    float* out = (float*)d_out;

    int NN = in_sizes[0] / HID;   // 50000
    int E  = in_sizes[1] / 2;     // 800000
    int ET = E + NN;

    char* ws = (char*)d_ws;
    size_t off = 0;
    auto alloc = [&](size_t bytes) -> char* {
        char* p = ws + off;
        off += (bytes + 255) & ~(size_t)255;
        return p;
    };
    unsigned short* bufH = (unsigned short*)alloc((size_t)NN * C2 * 2);
    unsigned short* bufO = (unsigned short*)alloc((size_t)NN * C2 * 2);
    float* asd = (float*)alloc((size_t)NN * 4 * sizeof(float));
    int* rs    = (int*)alloc((size_t)(NN + 1) * 4);
    int* cur   = (int*)alloc((size_t)NN * 4);
    int* csr   = (int*)alloc((size_t)ET * 4);
    int* part  = (int*)alloc(1024);
    unsigned short* W1p  = (unsigned short*)alloc((size_t)HID * C2 * 2);  // packed
    unsigned short* W2p  = (unsigned short*)alloc((size_t)C2 * C2 * 2);
    unsigned short* Wp1p = (unsigned short*)alloc((size_t)C2 * HID * 2);

    int nchunk = (NN + 255) / 256;
    int eblk   = (ET + 255) / 256;

    // weight staging (bf16 + MFMA-fragment packing)
    packB<<<(HID * C2 / 8 + 255) / 256, 256, 0, stream>>>(W1, W1p, HID, C2);
    packB<<<(C2 * C2 / 8 + 255) / 256, 256, 0, stream>>>(W2, W2p, C2, C2);
    packB<<<(C2 * HID / 8 + 255) / 256, 256, 0, stream>>>(Wp1, Wp1p, C2, HID);

    // CSR build
    zero_int<<<nchunk, 256, 0, stream>>>(cur, NN);
    hist_kernel<<<eblk, 256, 0, stream>>>(ei, cur, E, NN);
    scanA<<<nchunk, 256, 0, stream>>>(cur, rs, part, NN);
    scanB<<<1, 256, 0, stream>>>(part, nchunk);
    scanC<<<nchunk, 256, 0, stream>>>(rs, part, cur, NN, ET);
    scatter_kernel<<<eblk, 256, 0, stream>>>(ei, cur, csr, E, NN);

    const int G = 4;
    int mtiles = NN / 16;                     // 3125
    int groups = (mtiles + G - 1) / G;        // 782
    int wgemm = groups * 2;                   // ngrp=2
    // layer 1 (A = fp32 x, cvt in-register) + fused alpha dots
    gemm_alpha<true, G><<<(wgemm + 3) / 4, 256, 0, stream>>>(x, W1p, as1, ad1, asd, bufH, NN, C2, HID);
    agg_kernel<<<(NN + 3) / 4, 256, 0, stream>>>(rs, csr, bufH, asd, b1, bufO, NN);
    // layer 2
    gemm_alpha<false, G><<<(wgemm + 3) / 4, 256, 0, stream>>>(bufO, W2p, as2, ad2, asd, bufH, NN, C2, C2);
    agg_kernel<<<(NN + 3) / 4, 256, 0, stream>>>(rs, csr, bufH, asd, b2, bufO, NN);
    // post-MLP fully fused
    gemm_final<G><<<(groups + 3) / 4, 256, 0, stream>>>(bufO, Wp1p, bp1, Wp2, bp2, out, NN, C2);
}

// Round 7
// 385.042 us; speedup vs baseline: 1.0264x; 1.0264x over previous
//
#include <hip/hip_runtime.h>

#define HID 128
#define C2 256   // HEADS*HID
#define NEG 0.2f

typedef __bf16 v8bf __attribute__((ext_vector_type(8)));
typedef float  v4f  __attribute__((ext_vector_type(4)));
typedef unsigned short us8 __attribute__((ext_vector_type(8)));

__device__ __forceinline__ float bf2f(unsigned short u) {
    union { float f; unsigned int i; } v; v.i = ((unsigned int)u) << 16; return v.f;
}
__device__ __forceinline__ unsigned short f2bf(float f) {
    union { float f; unsigned int i; } v; v.f = f;
    unsigned int r = v.i + 0x7FFFu + ((v.i >> 16) & 1u);
    return (unsigned short)(r >> 16);
}
__device__ __forceinline__ float lrelu(float x) { return x > 0.f ? x : NEG * x; }

// ---------------- pack W[K,N] fp32 -> bf16 MFMA-B-fragment order ----------------
// frag idx = (nt*ksteps + k0)*64 + lane; element j = W[k0*32+(lane>>4)*8+j][nt*16+(lane&15)]
__global__ __launch_bounds__(256) void packB(const float* __restrict__ W,
                                             unsigned short* __restrict__ out,
                                             int K, int N) {
    int idx = blockIdx.x * 256 + threadIdx.x;
    int ksteps = K >> 5;
    int total = (N >> 4) * ksteps * 64;
    if (idx >= total) return;
    int lane = idx & 63;
    int rest = idx >> 6;
    int nt = rest / ksteps, k0 = rest - nt * ksteps;
    int n = nt * 16 + (lane & 15);
    int kb = k0 * 32 + (lane >> 4) * 8;
    us8 v;
#pragma unroll
    for (int j = 0; j < 8; ++j) v[j] = f2bf(W[(size_t)(kb + j) * N + n]);
    *(us8*)(out + (size_t)idx * 8) = v;
}

// ---------------- CSR build ----------------
__global__ void zero_int(int* p, int n) {
    int i = blockIdx.x * 256 + threadIdx.x;
    if (i < n) p[i] = 0;
}

__global__ void hist_kernel(const int* __restrict__ ei, int* __restrict__ cnt, int E, int N) {
    int i = blockIdx.x * 256 + threadIdx.x;
    if (i >= E + N) return;
    int d = (i < E) ? ei[E + i] : (i - E);
    atomicAdd(&cnt[d], 1);
}

__global__ __launch_bounds__(256) void scanA(const int* __restrict__ cnt, int* __restrict__ rs,
                                             int* __restrict__ part, int N) {
    __shared__ int s[256];
    int t = threadIdx.x, i = blockIdx.x * 256 + t;
    int v = (i < N) ? cnt[i] : 0;
    s[t] = v; __syncthreads();
    for (int off = 1; off < 256; off <<= 1) {
        int x = (t >= off) ? s[t - off] : 0;
        __syncthreads();
        s[t] += x;
        __syncthreads();
    }
    if (i < N) rs[i] = s[t] - v;
    if (t == 255) part[blockIdx.x] = s[255];
}

__global__ __launch_bounds__(256) void scanB(int* __restrict__ part, int n) {
    __shared__ int s[256];
    int t = threadIdx.x;
    int v = (t < n) ? part[t] : 0;
    s[t] = v; __syncthreads();
    for (int off = 1; off < 256; off <<= 1) {
        int x = (t >= off) ? s[t - off] : 0;
        __syncthreads();
        s[t] += x;
        __syncthreads();
    }
    if (t < n) part[t] = s[t] - v;
}

__global__ void scanC(int* __restrict__ rs, const int* __restrict__ part,
                      int* __restrict__ cur, int N, int ET) {
    int i = blockIdx.x * 256 + threadIdx.x;
    if (i < N) {
        int v = rs[i] + part[blockIdx.x];
        rs[i] = v;
        cur[i] = v;
    }
    if (i == 0) rs[N] = ET;
}

__global__ void scatter_kernel(const int* __restrict__ ei, int* __restrict__ cur,
                               int* __restrict__ csr, int E, int N) {
    int i = blockIdx.x * 256 + threadIdx.x;
    if (i >= E + N) return;
    int s, d;
    if (i < E) { s = ei[i]; d = ei[E + i]; } else { s = d = i - E; }
    int pos = atomicAdd(&cur[d], 1);
    csr[pos] = s;
}

// ---------------- GEMM (layers 1,2): fused alpha dots; G m-tiles per wave ----------------
template<bool AFP32, int G>
__global__ __launch_bounds__(256) void gemm_alpha(const void* __restrict__ Av,
                                                  const unsigned short* __restrict__ Bp,
                                                  const float* __restrict__ asrc,
                                                  const float* __restrict__ adst,
                                                  float* __restrict__ asd,
                                                  unsigned short* __restrict__ C,
                                                  int M, int N, int K) {
    int ksteps = K >> 5;
    int ngrp = N >> 7;
    int mtiles = M >> 4;
    int groups = (mtiles + G - 1) / G;
    int w = (blockIdx.x << 2) + (threadIdx.x >> 6);
    int mp = w / ngrp, g = w - mp * ngrp;
    if (mp >= groups) return;
    int lane = threadIdx.x & 63;
    int l16 = lane & 15, quad = lane >> 4;

    int mrow[G];
#pragma unroll
    for (int gi = 0; gi < G; ++gi) {
        int mt = mp * G + gi;
        mrow[gi] = (mt < mtiles ? mt : mtiles - 1) * 16 + l16;
    }

    const unsigned short* Bf = Bp + ((size_t)(g * 8) * ksteps << 9) + lane * 8;
    v4f acc[G][8];
#pragma unroll
    for (int gi = 0; gi < G; ++gi)
#pragma unroll
        for (int t = 0; t < 8; ++t) acc[gi][t] = (v4f){0, 0, 0, 0};

    for (int k0 = 0; k0 < ksteps; ++k0) {
        v8bf a[G];
        if (AFP32) {
            const float* A = (const float*)Av;
#pragma unroll
            for (int gi = 0; gi < G; ++gi) {
                const float* p = A + (size_t)mrow[gi] * K + k0 * 32 + quad * 8;
                float4 u0 = *(const float4*)p, u1 = *(const float4*)(p + 4);
                a[gi][0]=(__bf16)u0.x; a[gi][1]=(__bf16)u0.y; a[gi][2]=(__bf16)u0.z; a[gi][3]=(__bf16)u0.w;
                a[gi][4]=(__bf16)u1.x; a[gi][5]=(__bf16)u1.y; a[gi][6]=(__bf16)u1.z; a[gi][7]=(__bf16)u1.w;
            }
        } else {
            const unsigned short* A = (const unsigned short*)Av;
#pragma unroll
            for (int gi = 0; gi < G; ++gi)
                a[gi] = *(const v8bf*)(A + (size_t)mrow[gi] * K + k0 * 32 + quad * 8);
        }
#pragma unroll
        for (int t = 0; t < 8; ++t) {
            v8bf bfr = *(const v8bf*)(Bf + ((size_t)(t * ksteps + k0) << 9));
#pragma unroll
            for (int gi = 0; gi < G; ++gi)
                acc[gi][t] = __builtin_amdgcn_mfma_f32_16x16x32_bf16(a[gi], bfr, acc[gi][t], 0, 0, 0);
        }
    }

    int n0 = g << 7;
    float sv[8], dv[8];
#pragma unroll
    for (int t = 0; t < 8; ++t) {
        int col = n0 + t * 16 + l16;
        sv[t] = asrc[col];
        dv[t] = adst[col];
    }
#pragma unroll
    for (int gi = 0; gi < G; ++gi) {
        int mt = mp * G + gi;
        if (mt >= mtiles) break;
        int row0 = mt * 16 + quad * 4;
#pragma unroll
        for (int r = 0; r < 4; ++r) {
            float sa = 0.f, sd = 0.f;
#pragma unroll
            for (int t = 0; t < 8; ++t) {
                int col = n0 + t * 16 + l16;
                unsigned short hb = f2bf(acc[gi][t][r]);
                C[(size_t)(row0 + r) * N + col] = hb;
                float hv = bf2f(hb);
                sa += hv * sv[t];
                sd += hv * dv[t];
            }
#pragma unroll
            for (int off = 8; off; off >>= 1) {
                sa += __shfl_xor(sa, off);
                sd += __shfl_xor(sd, off);
            }
            if (l16 == 0) {
                int row = row0 + r;
                asd[(size_t)row * 4 + g]     = sa;
                asd[(size_t)row * 4 + 2 + g] = sd;
            }
        }
    }
}

// ---------------- single-pass agg: batch-64 weight precompute + shuffle-broadcast gather ----------------
// batch phase: lane l computes src+weights for edge b+l (1 csr instr + 1 asd instr per 64 edges).
// gather phase: 2 edges/iter via ds_bpermute broadcast of (src, w0, w1); 1 h-load instr per edge.
__global__ __launch_bounds__(256) void agg_kernel(const int* __restrict__ rs,
                                                  const int* __restrict__ csr,
                                                  const unsigned short* __restrict__ h,
                                                  const float* __restrict__ asd,
                                                  const float* __restrict__ bias,
                                                  unsigned short* __restrict__ out, int N) {
    int d = blockIdx.x * 4 + (threadIdx.x >> 6);
    if (d >= N) return;
    int lane = threadIdx.x & 63;
    int beg = rs[d], end = rs[d + 1];
    float2 adp = *(const float2*)(asd + (size_t)d * 4 + 2);   // ad_h0, ad_h1
    int e2 = lane >> 5;          // edge of the pair
    int sub = lane & 31;
    int head = sub >> 4;
    int cbase = sub * 8;
    const unsigned short* hc = h + cbase;
    float a[8];
#pragma unroll
    for (int j = 0; j < 8; ++j) a[j] = 0.f;
    float den0 = 0.f, den1 = 0.f;

    for (int b = beg; b < end; b += 64) {
        int nb = end - b; if (nb > 64) nb = 64;
        // batch phase: lane l -> edge b+l
        int sE = 0; float w0 = 0.f, w1 = 0.f;
        if (lane < nb) {
            sE = csr[b + lane];
            float2 as = *(const float2*)(asd + (size_t)sE * 4);
            w0 = __expf(lrelu(as.x + adp.x));
            w1 = __expf(lrelu(as.y + adp.y));
        }
        den0 += w0; den1 += w1;
        // gather phase: 2 edges per iteration
        int nbr = (nb + 1) & ~1;
#pragma unroll 2
        for (int i = 0; i < nbr; i += 2) {
            int idx = i + e2;
            int s    = __shfl(sE, idx);
            float v0 = __shfl(w0, idx);
            float v1 = __shfl(w1, idx);
            float wgt = head ? v1 : v0;      // 0 for padded idx==nb slot
            us8 hv = *(const us8*)(hc + (size_t)s * C2);
#pragma unroll
            for (int j = 0; j < 8; ++j) a[j] += wgt * bf2f(hv[j]);
        }
    }
    // fold the two edge-halves, reduce den across wave
#pragma unroll
    for (int j = 0; j < 8; ++j) a[j] += __shfl_xor(a[j], 32);
#pragma unroll
    for (int off = 32; off; off >>= 1) {
        den0 += __shfl_xor(den0, off);
        den1 += __shfl_xor(den1, off);
    }
    if (e2 == 0) {
        float rden = 1.f / ((head ? den1 : den0) + 1e-16f);
        us8 o;
#pragma unroll
        for (int j = 0; j < 8; ++j) o[j] = f2bf(fmaxf(a[j] * rden + bias[cbase + j], 0.f));
        *(us8*)(out + (size_t)d * C2 + cbase) = o;
    }
}

// ---------------- post-MLP fused: t = A@Wp1 + bp1; out = sigmoid(t.Wp2 + bp2); G m-tiles/wave ----------------
template<int G>
__global__ __launch_bounds__(256) void gemm_final(const unsigned short* __restrict__ A,
                                                  const unsigned short* __restrict__ Bp,
                                                  const float* __restrict__ bp1,
                                                  const float* __restrict__ wp2,
                                                  const float* __restrict__ bp2,
                                                  float* __restrict__ out,
                                                  int M, int K) {
    int ksteps = K >> 5;                 // 8
    int mtiles = M >> 4;
    int groups = (mtiles + G - 1) / G;
    int mp = (blockIdx.x << 2) + (threadIdx.x >> 6);
    if (mp >= groups) return;
    int lane = threadIdx.x & 63;
    int l16 = lane & 15, quad = lane >> 4;

    int mrow[G];
#pragma unroll
    for (int gi = 0; gi < G; ++gi) {
        int mt = mp * G + gi;
        mrow[gi] = (mt < mtiles ? mt : mtiles - 1) * 16 + l16;
    }

    const unsigned short* Bf = Bp + lane * 8;
    v4f acc[G][8];
#pragma unroll
    for (int gi = 0; gi < G; ++gi)
#pragma unroll
        for (int t = 0; t < 8; ++t) acc[gi][t] = (v4f){0, 0, 0, 0};
    for (int k0 = 0; k0 < ksteps; ++k0) {
        v8bf a[G];
#pragma unroll
        for (int gi = 0; gi < G; ++gi)
            a[gi] = *(const v8bf*)(A + (size_t)mrow[gi] * K + k0 * 32 + quad * 8);
#pragma unroll
        for (int t = 0; t < 8; ++t) {
            v8bf bfr = *(const v8bf*)(Bf + ((size_t)(t * ksteps + k0) << 9));
#pragma unroll
            for (int gi = 0; gi < G; ++gi)
                acc[gi][t] = __builtin_amdgcn_mfma_f32_16x16x32_bf16(a[gi], bfr, acc[gi][t], 0, 0, 0);
        }
    }
    float wv[8], bv[8];
#pragma unroll
    for (int t = 0; t < 8; ++t) {
        int col = t * 16 + l16;
        wv[t] = wp2[col];
        bv[t] = bp1[col];
    }
    float bias2 = bp2[0];
#pragma unroll
    for (int gi = 0; gi < G; ++gi) {
        int mt = mp * G + gi;
        if (mt >= mtiles) break;
        int row0 = mt * 16 + quad * 4;
#pragma unroll
        for (int r = 0; r < 4; ++r) {
            float s = 0.f;
#pragma unroll
            for (int t = 0; t < 8; ++t) s += (acc[gi][t][r] + bv[t]) * wv[t];
#pragma unroll
            for (int off = 8; off; off >>= 1) s += __shfl_xor(s, off);
            if (l16 == 0) {
                float xv = s + bias2;
                out[row0 + r] = 1.f / (1.f + __expf(-xv));
            }
        }
    }
}

extern "C" void kernel_launch(void* const* d_in, const int* in_sizes, int n_in,
                              void* d_out, int out_size, void* d_ws, size_t ws_size,
                              hipStream_t stream) {
    const float* x   = (const float*)d_in[0];
    const int*   ei  = (const int*)d_in[1];
    const float* W1  = (const float*)d_in[2];
    const float* as1 = (const float*)d_in[3];
    const float* ad1 = (const float*)d_in[4];
    const float* b1  = (const float*)d_in[5];
    const float* W2  = (const float*)d_in[6];
    const float* as2 = (const float*)d_in[7];
    const float* ad2 = (const float*)d_in[8];
    const float* b2  = (const float*)d_in[9];
    const float* Wp1 = (const float*)d_in[10];
    const float* bp1 = (const float*)d_in[11];
    const float* Wp2 = (const float*)d_in[12];
    const float* bp2 = (const float*)d_in[13];
    float* out = (float*)d_out;

    int NN = in_sizes[0] / HID;   // 50000
    int E  = in_sizes[1] / 2;     // 800000
    int ET = E + NN;

    char* ws = (char*)d_ws;
    size_t off = 0;
    auto alloc = [&](size_t bytes) -> char* {
        char* p = ws + off;
        off += (bytes + 255) & ~(size_t)255;
        return p;
    };
    unsigned short* bufH = (unsigned short*)alloc((size_t)NN * C2 * 2);
    unsigned short* bufO = (unsigned short*)alloc((size_t)NN * C2 * 2);
    float* asd = (float*)alloc((size_t)NN * 4 * sizeof(float));
    int* rs    = (int*)alloc((size_t)(NN + 1) * 4);
    int* cur   = (int*)alloc((size_t)NN * 4);
    int* csr   = (int*)alloc((size_t)ET * 4);
    int* part  = (int*)alloc(1024);
    unsigned short* W1p  = (unsigned short*)alloc((size_t)HID * C2 * 2);  // packed
    unsigned short* W2p  = (unsigned short*)alloc((size_t)C2 * C2 * 2);
    unsigned short* Wp1p = (unsigned short*)alloc((size_t)C2 * HID * 2);

    int nchunk = (NN + 255) / 256;
    int eblk   = (ET + 255) / 256;

    // weight staging (bf16 + MFMA-fragment packing)
    packB<<<(HID * C2 / 8 + 255) / 256, 256, 0, stream>>>(W1, W1p, HID, C2);
    packB<<<(C2 * C2 / 8 + 255) / 256, 256, 0, stream>>>(W2, W2p, C2, C2);
    packB<<<(C2 * HID / 8 + 255) / 256, 256, 0, stream>>>(Wp1, Wp1p, C2, HID);

    // CSR build
    zero_int<<<nchunk, 256, 0, stream>>>(cur, NN);
    hist_kernel<<<eblk, 256, 0, stream>>>(ei, cur, E, NN);
    scanA<<<nchunk, 256, 0, stream>>>(cur, rs, part, NN);
    scanB<<<1, 256, 0, stream>>>(part, nchunk);
    scanC<<<nchunk, 256, 0, stream>>>(rs, part, cur, NN, ET);
    scatter_kernel<<<eblk, 256, 0, stream>>>(ei, cur, csr, E, NN);

    const int G = 2;
    int mtiles = NN / 16;                     // 3125
    int groups = (mtiles + G - 1) / G;
    int wgemm = groups * 2;                   // ngrp=2
    // layer 1 (A = fp32 x, cvt in-register) + fused alpha dots
    gemm_alpha<true, G><<<(wgemm + 3) / 4, 256, 0, stream>>>(x, W1p, as1, ad1, asd, bufH, NN, C2, HID);
    agg_kernel<<<(NN + 3) / 4, 256, 0, stream>>>(rs, csr, bufH, asd, b1, bufO, NN);
    // layer 2
    gemm_alpha<false, G><<<(wgemm + 3) / 4, 256, 0, stream>>>(bufO, W2p, as2, ad2, asd, bufH, NN, C2, C2);
    agg_kernel<<<(NN + 3) / 4, 256, 0, stream>>>(rs, csr, bufH, asd, b2, bufO, NN);
    // post-MLP fully fused
    gemm_final<G><<<(groups + 3) / 4, 256, 0, stream>>>(bufO, Wp1p, bp1, Wp2, bp2, out, NN, C2);
}